// Round 1
// 275.748 us; speedup vs baseline: 1.0016x; 1.0016x over previous
//
#include <hip/hip_runtime.h>
#include <stdint.h>

// Cost volume = 48-wide band of Gram matrix L^T R per (b,h), K = c = 128.
// bf16 MFMA 32x32x16. Memory-bound target ~47us (298 MB @ 6.3 TB/s).
// R5: continuous-flow staging. R matrix staged f32 via global_load_lds
//     (counted vmcnt, never drained to 0 in the loop); L staged via the
//     reg-pack path with issue-before-wait. bf16 pack for R moves to the
//     fragment-read side. Uniform per-wave VMEM counts (waves 8/9 issue
//     duplicate DMA) so all waitcnt arithmetic is wave-invariant.

typedef __bf16 bf16x8 __attribute__((ext_vector_type(8)));
typedef float floatx16 __attribute__((ext_vector_type(16)));

constexpr int W = 320, H = 96, C = 128, NB = 8, MAXD = 48;
constexpr int HW = H * W;        // 30720
constexpr int SC = 16;           // channels per stage
constexpr int NST = C / SC;      // 8 stages
constexpr int LBD = (SC / 2) * W;  // 2560 dwords: packed-L stage buffer
constexpr int ROFF = 2 * LBD;      // 5120: start of R region
constexpr int RBD = SC * W;        // 5120 dwords: f32-R stage buffer

__device__ __forceinline__ uint32_t pack_bf16x2(float a, float b) {
    // RNE f32->bf16; (c even -> low16, c odd -> high16) == MFMA k-order.
    uint32_t ua = __float_as_uint(a), ub = __float_as_uint(b);
    uint32_t lo = (ua + 0x7fffu + ((ua >> 16) & 1u)) >> 16;
    uint32_t hi = (ub + 0x7fffu + ((ub >> 16) & 1u)) & 0xffff0000u;
    return hi | lo;
}

__device__ __forceinline__ floatx16 mfma_bf16(bf16x8 a, uint4 b, floatx16 c) {
    return __builtin_amdgcn_mfma_f32_32x32x16_bf16(
        a, __builtin_bit_cast(bf16x8, b), c, 0, 0, 0);
}

// Direct global->LDS DMA. LDS dest is wave-uniform base + lane*SZ;
// global source is per-lane. SZ must be a literal (4 or 16).
#define GLDS(gp, lp, SZ)                                                   \
    __builtin_amdgcn_global_load_lds(                                      \
        (const __attribute__((address_space(1))) void*)(gp),               \
        (__attribute__((address_space(3))) void*)(lp), SZ, 0, 0)

__global__ __launch_bounds__(640, 5) void cost_volume_kernel(
    const float* __restrict__ Lg, const float* __restrict__ Rg,
    float* __restrict__ out)
{
    // 63360 B: staging region (15360 dw = packed-L dbuf + f32-R dbuf)
    // overlapped with epilogue scratch (10 waves * 48*33 f32 = 15840 dw).
    __shared__ uint32_t lds[15840];

    const int t    = threadIdx.x;
    const int lane = t & 63;
    const int p    = t >> 6;       // wave id = 32-wide x-tile id
    const int n    = lane & 31;
    const int half = lane >> 5;

    const int b = blockIdx.x / H;
    const int h = blockIdx.x % H;
    const int baseLR = b * (C * HW) + h * W;

    // ---- L staging (reg-pack path): thread t covers c-pair row rp, cols 4*c4..+3
    const int rp = t / 80;         // 0..7
    const int c4 = t % 80;
    const float* Lt = Lg + baseLR + 2 * rp * HW + 4 * c4;

    float4 l0, l1;                 // prefetch regs (8 VGPR)
    auto loadL = [&](int s) {
        const float* Lp = Lt + s * SC * HW;
        l0 = *(const float4*)(Lp);
        l1 = *(const float4*)(Lp + HW);
    };
    auto writeL = [&](int s) {
        uint32_t* d = lds + (s & 1) * LBD + rp * W + 4 * c4;
        uint4 v;
        v.x = pack_bf16x2(l0.x, l1.x);
        v.y = pack_bf16x2(l0.y, l1.y);
        v.z = pack_bf16x2(l0.z, l1.z);
        v.w = pack_bf16x2(l0.w, l1.w);
        *reinterpret_cast<uint4*>(d) = v;
    };

    // ---- R staging (DMA path): wave w stages f32 rows (w&7), (w&7)+8.
    // Waves 8,9 duplicate rows {0,8},{1,9}: benign identical-write race,
    // keeps per-wave outstanding-VMEM counts uniform (4 DMA/stage/wave).
    const int r0 = p & 7;
    auto dmaR = [&](int s) {
#pragma unroll
        for (int rr = 0; rr < 2; ++rr) {
            const int row = r0 + rr * 8;
            const float* g = Rg + baseLR + (s * SC + row) * HW;
            uint32_t* l = lds + ROFF + (s & 1) * RBD + row * W;
            GLDS(g + lane * 4, l, 16);        // floats 0..255 of the row
            GLDS(g + 256 + lane, l + 256, 4); // floats 256..319
        }
    };

    floatx16 acc0 = 0.f, acc1 = 0.f, acc2 = 0.f;  // q = p, p-1, p-2

    // ---- prologue: outstanding leaving = [R(0) x4][L(1) x2]
    loadL(0);
    dmaR(0);
    asm volatile("s_waitcnt vmcnt(4)" ::: "memory");  // wait L(0); R(0) stays in flight
    writeL(0);
    loadL(1);

#pragma unroll
    for (int s = 0; s < NST; ++s) {
        // issue next R stage first, then counted-wait for current stage:
        // outstanding before wait = [R(s) 4][L(s+1) 2][R(s+1) 4] -> vmcnt(6)
        // drains exactly R(s), leaving the 6 prefetch ops in flight.
        if (s + 1 < NST) {
            dmaR(s + 1);
            asm volatile("s_waitcnt vmcnt(6) lgkmcnt(0)" ::: "memory");
        } else {
            asm volatile("s_waitcnt vmcnt(0) lgkmcnt(0)" ::: "memory");
        }
        __builtin_amdgcn_s_barrier();   // barrier1: stage s globally visible
        asm volatile("" ::: "memory");

        // A fragment from packed-L: k = half*8 + j -> pair-rows half*4 + jj
        const uint32_t* La = lds + (s & 1) * LBD + half * (4 * W) + p * 32 + n;
        uint4 a4;
        a4.x = La[0 * W]; a4.y = La[1 * W]; a4.z = La[2 * W]; a4.w = La[3 * W];
        bf16x8 af = __builtin_bit_cast(bf16x8, a4);

        // B fragments from f32-R rows (pack on read): row j = half*8 + j
        const float* Rf = reinterpret_cast<const float*>(lds + ROFF + (s & 1) * RBD)
                        + half * (8 * W) + n;
        {
            const float* pb = Rf + 32 * p;
            uint4 b4;
            b4.x = pack_bf16x2(pb[0 * W], pb[1 * W]);
            b4.y = pack_bf16x2(pb[2 * W], pb[3 * W]);
            b4.z = pack_bf16x2(pb[4 * W], pb[5 * W]);
            b4.w = pack_bf16x2(pb[6 * W], pb[7 * W]);
            acc0 = mfma_bf16(af, b4, acc0);
        }
        if (p >= 1) {
            const float* pb = Rf + 32 * (p - 1);
            uint4 b4;
            b4.x = pack_bf16x2(pb[0 * W], pb[1 * W]);
            b4.y = pack_bf16x2(pb[2 * W], pb[3 * W]);
            b4.z = pack_bf16x2(pb[4 * W], pb[5 * W]);
            b4.w = pack_bf16x2(pb[6 * W], pb[7 * W]);
            acc1 = mfma_bf16(af, b4, acc1);
        }
        if (p >= 2) {
            const float* pb = Rf + 32 * (p - 2);
            uint4 b4;
            b4.x = pack_bf16x2(pb[0 * W], pb[1 * W]);
            b4.y = pack_bf16x2(pb[2 * W], pb[3 * W]);
            b4.z = pack_bf16x2(pb[4 * W], pb[5 * W]);
            b4.w = pack_bf16x2(pb[6 * W], pb[7 * W]);
            acc2 = mfma_bf16(af, b4, acc2);
        }

        // L for stage s+1: counted wait (R(s+1) x4 stays in flight), pack,
        // write other half-buffer, then immediately issue L(s+2).
        if (s + 1 < NST) {
            asm volatile("s_waitcnt vmcnt(4)" ::: "memory");  // drain L(s+1) only
            writeL(s + 1);
            if (s + 2 < NST) loadL(s + 2);
        }
        asm volatile("s_waitcnt lgkmcnt(0)" ::: "memory");
        __builtin_amdgcn_s_barrier();   // barrier2: all reads/writes of this
        asm volatile("" ::: "memory");  // stage's buffers are done -> reusable
    }

    __syncthreads();   // full drain before reusing LDS as scratch

    // ---- epilogue: band -> per-wave LDS transpose -> coalesced stores ----
    // D layout (verified): m = (r&3) + 8*(r>>2) + 4*half, col = n
    float* sS = reinterpret_cast<float*>(lds) + p * (MAXD * 33);
    const int ob = b * (MAXD * HW) + h * W + p * 32;
    constexpr float scale = 1.f / 128.f;

    if (p < 2) {  // only x<64 has an i>x zero triangle
        for (int e = lane; e < MAXD * 33; e += 64) sS[e] = 0.f;
    }

#define FILL_TILE(DP, ACC)                                                  \
    if (p >= (DP)) {                                                        \
        _Pragma("unroll")                                                   \
        for (int r = 0; r < 16; ++r) {                                      \
            int m = (r & 3) + 8 * (r >> 2) + 4 * half;                      \
            int i = 32 * (DP) + m - n;                                      \
            if (i >= 0 && i < MAXD)                                         \
                sS[i * 33 + m] = ACC[r] * scale;                            \
        }                                                                   \
    }
    FILL_TILE(0, acc0)
    FILL_TILE(1, acc1)
    FILL_TILE(2, acc2)
#undef FILL_TILE

#pragma unroll
    for (int e = 0; e < 24; ++e) {
        int idx = e * 64 + lane;
        int i = idx >> 5;        // disparity 0..47
        int m = idx & 31;        // x-local
        out[ob + i * HW + m] = sS[i * 33 + m];
    }
}

extern "C" void kernel_launch(void* const* d_in, const int* in_sizes, int n_in,
                              void* d_out, int out_size, void* d_ws, size_t ws_size,
                              hipStream_t stream) {
    const float* L = (const float*)d_in[0];
    const float* R = (const float*)d_in[1];
    float* out = (float*)d_out;
    cost_volume_kernel<<<dim3(NB * H), dim3(640), 0, stream>>>(L, R, out);
}